// Round 3
// baseline (69.966 us; speedup 1.0000x reference)
//
#include <hip/hip_runtime.h>
#include <hip/hip_cooperative_groups.h>

namespace cg = cooperative_groups;

// B=131072, S=4, D=128, H=1
//   u[b] = dot(x[b,0,:], w) + bias     (reads only first S-slice: 64 MB)
//   y[b] = u[b] + a*y[b-1],  a = weight_h[0,0]
// Single cooperative kernel: per-chunk dot + local scan (registers) ->
// grid.sync() -> redundant carry scan per block -> direct output write.

#define B_ROWS 131072
#define CHUNK  256
#define NCHUNK 512   // B_ROWS / CHUNK

template <int CTRL>
__device__ __forceinline__ float dpp_add(float s) {
    int v = __builtin_amdgcn_update_dpp(0, __builtin_bit_cast(int, s), CTRL, 0xF, 0xF, true);
    return s + __builtin_bit_cast(float, v);
}

__global__ __launch_bounds__(256) void k_fused(const float* __restrict__ x,
                                               const float* __restrict__ w,
                                               const float* __restrict__ wh_p,
                                               const float* __restrict__ bias,
                                               float* __restrict__ out,
                                               float* __restrict__ carry) {
    __shared__ float u_s[CHUNK];
    __shared__ float wl[4];
    __shared__ float ex_s;
    const int tid  = threadIdx.x;
    const int wv   = tid >> 6;          // wave 0..3
    const int lane = tid & 63;
    const int half = lane >> 5;         // row of the pair
    const int hl   = lane & 31;         // lane within half-wave
    const int k    = blockIdx.x;        // chunk id
    const int base = k * CHUNK;

    const float4 wvec = *reinterpret_cast<const float4*>(w + hl * 4);
    const float  bs   = bias[0];
    const float* xp = x + (size_t)(base + wv * 64 + half) * 512 + hl * 4;

    // ---- Phase 1a: dot for 256 rows (2 rows/wave/iter, 512B coalesced per row) ----
#pragma unroll 8
    for (int r = 0; r < 32; ++r) {
        const float4 xv = *reinterpret_cast<const float4*>(xp + (size_t)r * 1024);
        float s = fmaf(xv.x, wvec.x, fmaf(xv.y, wvec.y, fmaf(xv.z, wvec.z, xv.w * wvec.w)));
        s = dpp_add<0xB1>(s);    // xor1 (quad_perm)
        s = dpp_add<0x4E>(s);    // xor2 (quad_perm)
        s = dpp_add<0x141>(s);   // row_half_mirror
        s = dpp_add<0x140>(s);   // row_mirror
        s += __shfl_xor(s, 16, 64);
        if (hl == 0) u_s[wv * 64 + r * 2 + half] = s + bs;
    }
    __syncthreads();

    // ---- Phase 1b: in-block weighted inclusive scan p_i = u_i + a*p_{i-1} ----
    const float a = wh_p[0];
    float c = u_s[tid];
    float fstep = a;
#pragma unroll
    for (int s = 1; s < 64; s <<= 1) {
        float prev = __shfl_up(c, (unsigned)s, 64);
        if (lane >= s) c = fmaf(prev, fstep, c);
        fstep *= fstep;
    }
    const float f64 = fstep;            // a^64
    // a^(lane+1) by binary powering (6 bits of lane)
    float apw = a, bse = a;
#pragma unroll
    for (int b = 0; b < 6; ++b) { if (lane & (1 << b)) apw *= bse; bse *= bse; }

    if (lane == 63) wl[wv] = c;
    __syncthreads();
    if (wv > 0) {
        float seed = wl[0];
#pragma unroll
        for (int j = 1; j < 4; ++j) if (j < wv) seed = fmaf(seed, f64, wl[j]);
        c = fmaf(seed, apw, c);         // block-wide inclusive prefix
    }
    if (tid == CHUNK - 1) carry[k] = c;

    // ---- grid-wide barrier: all carries visible ----
    cg::this_grid().sync();

    // ---- Phase 2: every block scans all 512 carries, picks ex_k = P_{k-1} ----
    const float A = [&]{ float t = f64 * f64; return t * t; }();   // a^256
    if (tid < 64) {
        float cv[8];
        float g = 0.0f;
#pragma unroll
        for (int i = 0; i < 8; ++i) { cv[i] = carry[lane * 8 + i]; g = fmaf(g, A, cv[i]); }
        float A8 = A * A; A8 *= A8; A8 *= A8;      // A^8
        float S = g, ff = A8;
#pragma unroll
        for (int s = 1; s < 64; s <<= 1) {
            float prev = __shfl_up(S, (unsigned)s, 64);
            if (lane >= s) S = fmaf(prev, ff, S);
            ff *= ff;
        }
        float Sprev = __shfl_up(S, 1, 64);          // S_{lane-1}
        if (k == 0) {
            if (lane == 0) ex_s = 0.0f;
        } else {
            const int m = k - 1, ls = m >> 3, is = m & 7;
            float P = (lane == 0) ? 0.0f : Sprev;
#pragma unroll
            for (int i = 0; i < 8; ++i) if (i <= is) P = fmaf(P, A, cv[i]);
            if (lane == ls) ex_s = P;               // P_{k-1}
        }
    }
    __syncthreads();

    // ---- Phase 3: y_i = p_i + a^(i+1) * ex ; direct coalesced store ----
    const float ex = ex_s;
    float pw = apw;                                  // a^(lane+1)
#pragma unroll
    for (int j = 0; j < 4; ++j) if (j < wv) pw *= f64;   // * a^(64*wv) -> a^(tid+1)
    const float y = fmaf(pw, ex, c);
    out[base + tid] = y;
    if (k == NCHUNK - 1 && tid == CHUNK - 1) {       // y_h duplicated tail
        out[B_ROWS]     = y;
        out[B_ROWS + 1] = y;
    }
}

extern "C" void kernel_launch(void* const* d_in, const int* in_sizes, int n_in,
                              void* d_out, int out_size, void* d_ws, size_t ws_size,
                              hipStream_t stream) {
    const float* x    = (const float*)d_in[0];   // (131072, 4, 128) f32
    const float* w    = (const float*)d_in[1];   // (128, 1) f32
    const float* wh   = (const float*)d_in[2];   // (1, 1) f32
    const float* bias = (const float*)d_in[3];   // (1,) f32
    float* out   = (float*)d_out;                // 131074 f32
    float* carry = (float*)d_ws;                 // NCHUNK floats

    void* args[] = { (void*)&x, (void*)&w, (void*)&wh, (void*)&bias,
                     (void*)&out, (void*)&carry };
    hipLaunchCooperativeKernel((const void*)k_fused, dim3(NCHUNK), dim3(256),
                               args, 0, stream);
}

// Round 4
// 29.529 us; speedup vs baseline: 2.3694x; 2.3694x over previous
//
#include <hip/hip_runtime.h>

// B=131072, S=4, D=128, H=1
//   u[b] = dot(x[b,0,:], w) + bias     (reads only first S-slice: 64 MB)
//   y[b] = u[b] + a*y[b-1],  a = weight_h[0,0]
// SINGLE regular kernel: per-chunk dot + local scan in registers, then
// ticket-ordered decoupled lookback over chunk aggregates (rocPRIM-style),
// then direct output write. No cooperative launch, no extra kernels.

#define B_ROWS 131072
#define CHUNK  256
#define NCHUNK 512   // B_ROWS / CHUNK
#define MAGIC  0x7C3A9E51u

template <int CTRL>
__device__ __forceinline__ float dpp_add(float s) {
    int v = __builtin_amdgcn_update_dpp(0, __builtin_bit_cast(int, s), CTRL, 0xF, 0xF, true);
    return s + __builtin_bit_cast(float, v);
}

__global__ __launch_bounds__(256) void k_fused(const float* __restrict__ x,
                                               const float* __restrict__ w,
                                               const float* __restrict__ wh_p,
                                               const float* __restrict__ bias,
                                               float* __restrict__ out,
                                               unsigned long long* __restrict__ pk,
                                               unsigned int* __restrict__ ticket) {
    __shared__ float u_s[CHUNK];
    __shared__ float wl[4];
    __shared__ float ex_s;
    __shared__ int   sh_vt;
    const int tid  = threadIdx.x;
    const int wv   = tid >> 6;          // wave 0..3
    const int lane = tid & 63;
    const int half = lane >> 5;         // row of the pair
    const int hl   = lane & 31;         // lane within half-wave

    // Ticket: guarantees all predecessor chunks already started (deadlock-free
    // lookback); &511 self-wraps across graph replays without a reset kernel.
    if (tid == 0) sh_vt = (int)(atomicAdd(ticket, 1u) & (NCHUNK - 1));
    __syncthreads();
    const int k    = sh_vt;             // chunk id
    const int base = k * CHUNK;

    const float4 wvec = *reinterpret_cast<const float4*>(w + hl * 4);
    const float  bs   = bias[0];
    const float* xp = x + (size_t)(base + wv * 64 + half) * 512 + hl * 4;

    // ---- Phase 1a: dot for 256 rows (2 rows/wave/iter, 512B coalesced) ----
#pragma unroll 8
    for (int r = 0; r < 32; ++r) {
        const float4 xv = *reinterpret_cast<const float4*>(xp + (size_t)r * 1024);
        float s = fmaf(xv.x, wvec.x, fmaf(xv.y, wvec.y, fmaf(xv.z, wvec.z, xv.w * wvec.w)));
        s = dpp_add<0xB1>(s);    // xor1 (quad_perm)
        s = dpp_add<0x4E>(s);    // xor2 (quad_perm)
        s = dpp_add<0x141>(s);   // row_half_mirror
        s = dpp_add<0x140>(s);   // row_mirror
        s += __shfl_xor(s, 16, 64);
        if (hl == 0) u_s[wv * 64 + r * 2 + half] = s + bs;
    }
    __syncthreads();

    // ---- Phase 1b: in-block weighted inclusive scan p_i = u_i + a*p_{i-1} ----
    const float a = wh_p[0];
    float c = u_s[tid];
    float fstep = a;
#pragma unroll
    for (int s = 1; s < 64; s <<= 1) {
        float prev = __shfl_up(c, (unsigned)s, 64);
        if (lane >= s) c = fmaf(prev, fstep, c);
        fstep *= fstep;
    }
    const float f64 = fstep;            // a^64
    // a^(lane+1) by binary powering (6 bits of lane)
    float apw = a, bse = a;
#pragma unroll
    for (int b = 0; b < 6; ++b) { if (lane & (1 << b)) apw *= bse; bse *= bse; }

    if (lane == 63) wl[wv] = c;
    __syncthreads();
    if (wv > 0) {
        float seed = wl[0];
#pragma unroll
        for (int j = 1; j < 4; ++j) if (j < wv) seed = fmaf(seed, f64, wl[j]);
        c = fmaf(seed, apw, c);         // block-wide inclusive prefix
    }

    // ---- Publish chunk aggregate ASAP (value packed WITH flag: no fences) ----
    if (tid == CHUNK - 1) {
        unsigned long long q =
            ((unsigned long long)__float_as_uint(c) << 32) | (unsigned long long)MAGIC;
        __hip_atomic_store(&pk[k], q, __ATOMIC_RELAXED, __HIP_MEMORY_SCOPE_AGENT);
    }

    // ---- Lookback (wave 0): ex = P_{k-1} from aggregates, fixed 64-wide windows ----
    if (tid < 64) {
        float t2 = f64 * f64;           // a^128
        const float A = t2 * t2;        // a^256 = per-chunk coefficient
        float ex = 0.0f;
        const int n = k;                // predecessor count
        for (int j0 = 0; j0 < n; j0 += 64) {
            const int t = min(64, n - j0);
            float cj = 0.0f;
            if (lane < t) {
                unsigned long long q;
                do {
                    q = __hip_atomic_load(&pk[j0 + lane], __ATOMIC_RELAXED,
                                          __HIP_MEMORY_SCOPE_AGENT);
                } while ((unsigned int)q != MAGIC);
                cj = __uint_as_float((unsigned int)(q >> 32));
            }
            // weighted inclusive scan over lanes with factor A
            float P = cj, ff = A;
#pragma unroll
            for (int s = 1; s < 64; s <<= 1) {
                float prev = __shfl_up(P, (unsigned)s, 64);
                if (lane >= s) P = fmaf(prev, ff, P);
                ff *= ff;
            }
            const float S = __shfl(P, t - 1, 64);
            // At = A^t, t in [1,64] (7 bits)
            float At = 1.0f, bb = A;
#pragma unroll
            for (int b = 0; b < 7; ++b) { if (t & (1 << b)) At *= bb; bb *= bb; }
            ex = fmaf(ex, At, S);       // Horner across windows (fixed order)
        }
        if (lane == 0) ex_s = ex;       // k==0: loop skipped, ex=0
    }
    __syncthreads();

    // ---- Phase 3: y_i = p_i + a^(i+1) * ex ; direct coalesced store ----
    const float ex = ex_s;
    float pw = apw;                     // a^(lane+1)
#pragma unroll
    for (int j = 0; j < 4; ++j) if (j < wv) pw *= f64;   // -> a^(tid+1)
    const float y = fmaf(pw, ex, c);
    out[base + tid] = y;
    if (k == NCHUNK - 1 && tid == CHUNK - 1) {           // y_h duplicated tail
        out[B_ROWS]     = y;
        out[B_ROWS + 1] = y;
    }
}

extern "C" void kernel_launch(void* const* d_in, const int* in_sizes, int n_in,
                              void* d_out, int out_size, void* d_ws, size_t ws_size,
                              hipStream_t stream) {
    const float* x    = (const float*)d_in[0];   // (131072, 4, 128) f32
    const float* w    = (const float*)d_in[1];   // (128, 1) f32
    const float* wh   = (const float*)d_in[2];   // (1, 1) f32
    const float* bias = (const float*)d_in[3];   // (1,) f32
    float* out = (float*)d_out;                  // 131074 f32

    unsigned long long* pk = (unsigned long long*)d_ws;      // NCHUNK qwords
    unsigned int* ticket   = (unsigned int*)(pk + NCHUNK);   // 1 dword

    k_fused<<<NCHUNK, 256, 0, stream>>>(x, w, wh, bias, out, pk, ticket);
}

// Round 5
// 24.118 us; speedup vs baseline: 2.9010x; 1.2243x over previous
//
#include <hip/hip_runtime.h>

// B=131072, S=4, D=128, H=1
//   u[b] = dot(x[b,0,:], w) + bias     (reads only first S-slice: 64 MB)
//   y[b] = u[b] + a*y[b-1],  a = weight_h[0,0]
// SINGLE regular kernel. Chunk id = blockIdx (512 blocks << 2048-block
// residency capacity -> lookback is deadlock-free without tickets).
// Per-chunk dot + in-register weighted scan -> publish packed aggregate ->
// 4-wave-parallel windowed lookback with s_sleep backoff -> direct write.

#define B_ROWS 131072
#define CHUNK  256
#define NCHUNK 512   // B_ROWS / CHUNK
#define MAGIC  0x7C3A9E51u

template <int CTRL>
__device__ __forceinline__ float dpp_add(float s) {
    int v = __builtin_amdgcn_update_dpp(0, __builtin_bit_cast(int, s), CTRL, 0xF, 0xF, true);
    return s + __builtin_bit_cast(float, v);
}

__global__ __launch_bounds__(256) void k_fused(const float* __restrict__ x,
                                               const float* __restrict__ w,
                                               const float* __restrict__ wh_p,
                                               const float* __restrict__ bias,
                                               float* __restrict__ out,
                                               unsigned long long* __restrict__ pk) {
    __shared__ float u_s[CHUNK];
    __shared__ float wl[4];
    __shared__ float Sw[8];             // per-window weighted sums
    __shared__ float ex_s;
    const int tid  = threadIdx.x;
    const int wv   = tid >> 6;          // wave 0..3
    const int lane = tid & 63;
    const int half = lane >> 5;         // row of the pair
    const int hl   = lane & 31;         // lane within half-wave
    const int k    = blockIdx.x;        // chunk id (no ticket: blocks co-resident)
    const int base = k * CHUNK;

    const float4 wvec = *reinterpret_cast<const float4*>(w + hl * 4);
    const float  bs   = bias[0];
    const float* xp = x + (size_t)(base + wv * 64 + half) * 512 + hl * 4;

    // ---- Phase 1a: dot for 256 rows (2 rows/wave/iter, 512B coalesced) ----
#pragma unroll 8
    for (int r = 0; r < 32; ++r) {
        const float4 xv = *reinterpret_cast<const float4*>(xp + (size_t)r * 1024);
        float s = fmaf(xv.x, wvec.x, fmaf(xv.y, wvec.y, fmaf(xv.z, wvec.z, xv.w * wvec.w)));
        s = dpp_add<0xB1>(s);    // xor1 (quad_perm)
        s = dpp_add<0x4E>(s);    // xor2 (quad_perm)
        s = dpp_add<0x141>(s);   // row_half_mirror
        s = dpp_add<0x140>(s);   // row_mirror
        s += __shfl_xor(s, 16, 64);
        if (hl == 0) u_s[wv * 64 + r * 2 + half] = s + bs;
    }
    __syncthreads();

    // ---- Phase 1b: in-block weighted inclusive scan p_i = u_i + a*p_{i-1} ----
    const float a = wh_p[0];
    float c = u_s[tid];
    float fstep = a;
#pragma unroll
    for (int s = 1; s < 64; s <<= 1) {
        float prev = __shfl_up(c, (unsigned)s, 64);
        if (lane >= s) c = fmaf(prev, fstep, c);
        fstep *= fstep;
    }
    const float f64 = fstep;            // a^64
    // a^(lane+1) by binary powering (6 bits of lane)
    float apw = a, bse = a;
#pragma unroll
    for (int b = 0; b < 6; ++b) { if (lane & (1 << b)) apw *= bse; bse *= bse; }

    if (lane == 63) wl[wv] = c;
    __syncthreads();
    if (wv > 0) {
        float seed = wl[0];
#pragma unroll
        for (int j = 1; j < 4; ++j) if (j < wv) seed = fmaf(seed, f64, wl[j]);
        c = fmaf(seed, apw, c);         // block-wide inclusive prefix
    }

    // ---- Publish chunk aggregate (value packed WITH flag: no fences) ----
    if (tid == CHUNK - 1) {
        unsigned long long q =
            ((unsigned long long)__float_as_uint(c) << 32) | (unsigned long long)MAGIC;
        __hip_atomic_store(&pk[k], q, __ATOMIC_RELAXED, __HIP_MEMORY_SCOPE_AGENT);
    }

    // ---- Lookback: nw=ceil(k/64) windows, distributed across the 4 waves ----
    const float Af = [&]{ float t2 = f64 * f64; return t2 * t2; }();   // a^256
    const int nw = (k + 63) >> 6;
    for (int wi = wv; wi < nw; wi += 4) {
        const int j0 = wi << 6;
        const int t  = min(64, k - j0);     // chunks in this window, 1..64
        float cj = 0.0f;
        if (lane < t) {
            unsigned long long q = __hip_atomic_load(&pk[j0 + lane], __ATOMIC_RELAXED,
                                                     __HIP_MEMORY_SCOPE_AGENT);
            while ((unsigned int)q != MAGIC) {
                __builtin_amdgcn_s_sleep(1);
                q = __hip_atomic_load(&pk[j0 + lane], __ATOMIC_RELAXED,
                                      __HIP_MEMORY_SCOPE_AGENT);
            }
            cj = __uint_as_float((unsigned int)(q >> 32));
        }
        // weighted inclusive scan; lane t-1 holds the window's weighted sum
        float P = cj, ff = Af;
#pragma unroll
        for (int s = 1; s < 64; s <<= 1) {
            float prev = __shfl_up(P, (unsigned)s, 64);
            if (lane >= s) P = fmaf(prev, ff, P);
            ff *= ff;
        }
        if (lane == t - 1) Sw[wi] = P;
    }
    __syncthreads();

    if (tid == 0) {
        float ex = 0.0f;
        if (nw > 0) {
            float A64 = Af;
#pragma unroll
            for (int i = 0; i < 6; ++i) A64 *= A64;       // Af^64
            for (int wi = 0; wi < nw - 1; ++wi) ex = fmaf(ex, A64, Sw[wi]);
            const int tl = k - ((nw - 1) << 6);           // last-window length 1..64
            float At = 1.0f, bb = Af;
#pragma unroll
            for (int b = 0; b < 7; ++b) { if (tl & (1 << b)) At *= bb; bb *= bb; }
            ex = fmaf(ex, At, Sw[nw - 1]);
        }
        ex_s = ex;
    }
    __syncthreads();

    // ---- Phase 3: y_i = p_i + a^(i+1) * ex ; direct coalesced store ----
    const float ex = ex_s;
    float pw = apw;                     // a^(lane+1)
#pragma unroll
    for (int j = 0; j < 4; ++j) if (j < wv) pw *= f64;   // -> a^(tid+1)
    const float y = fmaf(pw, ex, c);
    out[base + tid] = y;
    if (k == NCHUNK - 1 && tid == CHUNK - 1) {           // y_h duplicated tail
        out[B_ROWS]     = y;
        out[B_ROWS + 1] = y;
    }
}

extern "C" void kernel_launch(void* const* d_in, const int* in_sizes, int n_in,
                              void* d_out, int out_size, void* d_ws, size_t ws_size,
                              hipStream_t stream) {
    const float* x    = (const float*)d_in[0];   // (131072, 4, 128) f32
    const float* w    = (const float*)d_in[1];   // (128, 1) f32
    const float* wh   = (const float*)d_in[2];   // (1, 1) f32
    const float* bias = (const float*)d_in[3];   // (1,) f32
    float* out = (float*)d_out;                  // 131074 f32

    unsigned long long* pk = (unsigned long long*)d_ws;  // NCHUNK qwords

    k_fused<<<NCHUNK, 256, 0, stream>>>(x, w, wh, bias, out, pk);
}

// Round 6
// 21.292 us; speedup vs baseline: 3.2860x; 1.1327x over previous
//
#include <hip/hip_runtime.h>

// B=131072, S=4, D=128, H=1
//   u[b] = dot(x[b,0,:], w) + bias     (reads only first S-slice: 64 MB)
//   y[b] = u[b] + a*y[b-1],  a = weight_h[0,0]
// K1: pure streaming dot at FULL occupancy (2048 blocks, 32 waves/CU).
// K2: fused scan + decoupled lookback + write (512 blocks, u -> out).

#define B_ROWS 131072
#define CHUNK  256
#define NCHUNK 512   // B_ROWS / CHUNK
#define MAGIC  0x7C3A9E51u

template <int CTRL>
__device__ __forceinline__ float dpp_add(float s) {
    int v = __builtin_amdgcn_update_dpp(0, __builtin_bit_cast(int, s), CTRL, 0xF, 0xF, true);
    return s + __builtin_bit_cast(float, v);
}

// ---- K1: per-row dot. Half-wave per row, float4 loads, DPP reduce. ----
// 2048 blocks x 256 thr = 32 waves/CU: max outstanding loads during the stream.
__global__ __launch_bounds__(256) void k_dot(const float* __restrict__ x,
                                             const float* __restrict__ w,
                                             const float* __restrict__ bias,
                                             float* __restrict__ u) {
    const int gtid = blockIdx.x * 256 + threadIdx.x;
    const int wave = gtid >> 6;
    const int lane = threadIdx.x & 63;
    const int half = lane >> 5;        // which row of the pair
    const int hl   = lane & 31;        // lane within half-wave
    const float4 wv = *reinterpret_cast<const float4*>(w + hl * 4);
    const float  bs = bias[0];
    const int row0 = wave * 16;        // 16 rows per wave (8 iters x 2 rows)
#pragma unroll
    for (int r = 0; r < 8; ++r) {
        const int row = row0 + r * 2 + half;
        const float4 xv = *reinterpret_cast<const float4*>(x + (size_t)row * 512 + hl * 4);
        float s = fmaf(xv.x, wv.x, fmaf(xv.y, wv.y, fmaf(xv.z, wv.z, xv.w * wv.w)));
        s = dpp_add<0xB1>(s);    // xor1 (quad_perm)
        s = dpp_add<0x4E>(s);    // xor2 (quad_perm)
        s = dpp_add<0x141>(s);   // row_half_mirror
        s = dpp_add<0x140>(s);   // row_mirror
        s += __shfl_xor(s, 16, 64);
        if (hl == 0) u[row] = s + bs;
    }
}

// ---- K2: block scan of u + decoupled lookback + direct output write. ----
__global__ __launch_bounds__(256) void k_scan_apply(const float* __restrict__ u,
                                                    const float* __restrict__ wh_p,
                                                    unsigned long long* __restrict__ pk,
                                                    float* __restrict__ out) {
    __shared__ float wl[4];
    __shared__ float Sw[8];
    __shared__ float ex_s;
    const int tid  = threadIdx.x;
    const int wv   = tid >> 6;
    const int lane = tid & 63;
    const int k    = blockIdx.x;
    const int base = k * CHUNK;

    // u arrives coalesced, already in scan lane order: no LDS round-trip.
    const float a = wh_p[0];
    float c = u[base + tid];
    float fstep = a;
#pragma unroll
    for (int s = 1; s < 64; s <<= 1) {
        float prev = __shfl_up(c, (unsigned)s, 64);
        if (lane >= s) c = fmaf(prev, fstep, c);
        fstep *= fstep;
    }
    const float f64 = fstep;            // a^64
    float apw = a, bse = a;             // a^(lane+1)
#pragma unroll
    for (int b = 0; b < 6; ++b) { if (lane & (1 << b)) apw *= bse; bse *= bse; }

    if (lane == 63) wl[wv] = c;
    __syncthreads();
    if (wv > 0) {
        float seed = wl[0];
#pragma unroll
        for (int j = 1; j < 4; ++j) if (j < wv) seed = fmaf(seed, f64, wl[j]);
        c = fmaf(seed, apw, c);         // block-wide inclusive prefix
    }

    // Publish chunk aggregate (value packed WITH flag: no fences needed).
    if (tid == CHUNK - 1) {
        unsigned long long q =
            ((unsigned long long)__float_as_uint(c) << 32) | (unsigned long long)MAGIC;
        __hip_atomic_store(&pk[k], q, __ATOMIC_RELAXED, __HIP_MEMORY_SCOPE_AGENT);
    }

    // Lookback: nw windows of 64 predecessors, distributed across 4 waves.
    const float Af = [&]{ float t2 = f64 * f64; return t2 * t2; }();   // a^256
    const int nw = (k + 63) >> 6;
    for (int wi = wv; wi < nw; wi += 4) {
        const int j0 = wi << 6;
        const int t  = min(64, k - j0);     // chunks in this window, 1..64
        float cj = 0.0f;
        if (lane < t) {
            unsigned long long q = __hip_atomic_load(&pk[j0 + lane], __ATOMIC_RELAXED,
                                                     __HIP_MEMORY_SCOPE_AGENT);
            while ((unsigned int)q != MAGIC) {
                __builtin_amdgcn_s_sleep(1);
                q = __hip_atomic_load(&pk[j0 + lane], __ATOMIC_RELAXED,
                                      __HIP_MEMORY_SCOPE_AGENT);
            }
            cj = __uint_as_float((unsigned int)(q >> 32));
        }
        float P = cj, ff = Af;              // weighted scan; lane t-1 = window sum
#pragma unroll
        for (int s = 1; s < 64; s <<= 1) {
            float prev = __shfl_up(P, (unsigned)s, 64);
            if (lane >= s) P = fmaf(prev, ff, P);
            ff *= ff;
        }
        if (lane == t - 1) Sw[wi] = P;
    }
    __syncthreads();

    if (tid == 0) {
        float ex = 0.0f;
        if (nw > 0) {
            float A64 = Af;
#pragma unroll
            for (int i = 0; i < 6; ++i) A64 *= A64;       // Af^64
            for (int wi = 0; wi < nw - 1; ++wi) ex = fmaf(ex, A64, Sw[wi]);
            const int tl = k - ((nw - 1) << 6);           // last-window length 1..64
            float At = 1.0f, bb = Af;
#pragma unroll
            for (int b = 0; b < 7; ++b) { if (tl & (1 << b)) At *= bb; bb *= bb; }
            ex = fmaf(ex, At, Sw[nw - 1]);
        }
        ex_s = ex;
    }
    __syncthreads();

    // y_i = p_i + a^(i+1) * ex ; direct coalesced store.
    const float ex = ex_s;
    float pw = apw;
#pragma unroll
    for (int j = 0; j < 4; ++j) if (j < wv) pw *= f64;   // -> a^(tid+1)
    const float y = fmaf(pw, ex, c);
    out[base + tid] = y;
    if (k == NCHUNK - 1 && tid == CHUNK - 1) {           // y_h duplicated tail
        out[B_ROWS]     = y;
        out[B_ROWS + 1] = y;
    }
}

extern "C" void kernel_launch(void* const* d_in, const int* in_sizes, int n_in,
                              void* d_out, int out_size, void* d_ws, size_t ws_size,
                              hipStream_t stream) {
    const float* x    = (const float*)d_in[0];   // (131072, 4, 128) f32
    const float* w    = (const float*)d_in[1];   // (128, 1) f32
    const float* wh   = (const float*)d_in[2];   // (1, 1) f32
    const float* bias = (const float*)d_in[3];   // (1,) f32
    float* out = (float*)d_out;                  // 131074 f32

    float* u               = (float*)d_ws;                   // B_ROWS floats
    unsigned long long* pk = (unsigned long long*)(u + B_ROWS); // NCHUNK qwords

    k_dot<<<2048, 256, 0, stream>>>(x, w, bias, u);
    k_scan_apply<<<NCHUNK, 256, 0, stream>>>(u, wh, pk, out);
}